// Round 4
// baseline (159.377 us; speedup 1.0000x reference)
//
#include <hip/hip_runtime.h>
#include <math.h>

#define NT 128          // main kernel block size (2 waves)
#define NTG 256         // gram kernel block size

struct PW { const float* w[16]; int perp[16]; };

// ---------------------------------------------------------------------------
// Gram precompute: per node n, G00=<w0,w0>, G01=<w0,w1>, G11=<w1,w1> -> d_ws.
// ---------------------------------------------------------------------------
__global__ __launch_bounds__(NTG) void gram16(PW pw, float* __restrict__ g) {
    const int n = blockIdx.x;
    const float* __restrict__ W = pw.w[n];
    const int m = pw.perp[n];
    float s00 = 0.f, s01 = 0.f, s11 = 0.f;
    for (int e = threadIdx.x; e < m; e += NTG) {
        float a = W[e], b = W[m + e];
        s00 += a * a; s01 += a * b; s11 += b * b;
    }
    for (int off = 32; off > 0; off >>= 1) {
        s00 += __shfl_down(s00, off, 64);
        s01 += __shfl_down(s01, off, 64);
        s11 += __shfl_down(s11, off, 64);
    }
    __shared__ float red[4][3];
    const int lane = threadIdx.x & 63, wv = threadIdx.x >> 6;
    if (lane == 0) { red[wv][0] = s00; red[wv][1] = s01; red[wv][2] = s11; }
    __syncthreads();
    if (threadIdx.x == 0) {
        float t0 = 0.f, t1 = 0.f, t2 = 0.f;
        for (int i = 0; i < 4; i++) { t0 += red[i][0]; t1 += red[i][1]; t2 += red[i][2]; }
        g[n * 3 + 0] = t0; g[n * 3 + 1] = t1; g[n * 3 + 2] = t2;
    }
}

// ---------------------------------------------------------------------------
// LDS arena (floats), ONE sample per block. Big buffers BA..BD are renamed
// through the DAG (max 4 live at once); PB/SA/SB/SC are small scratch.
// ---------------------------------------------------------------------------
constexpr int BA = 0, BB = 1296, BC = 2592, BD = 3888;
constexpr int PBo = 5184, SA = 5400, SB = 5616, SC = 5832;
constexpr int ASZ = 5868;   // 23.47 KB -> 6 blocks/CU

// Stage t = al*w0 + be*w1 into lds[DST..DST+M).
template<int M, int DST>
__device__ __forceinline__ void tmat(float* __restrict__ lds, const float* __restrict__ W,
                                     float al, float be, int tid) {
    for (int e = tid; e < M; e += NT) lds[DST + e] = al * W[e] + be * W[M + e];
}

// ---------------------------------------------------------------------------
// out[x1,x2,y1,y2] = sum_{u,l} A[..]*B[..]; thread tile = TX x Y2 outputs.
// ---------------------------------------------------------------------------
template<int X1, int X2, int Y1, int Y2, int U, int L, int TX,
         int AX1, int AX2, int AU, int AL,
         int BU, int BLS, int BY1, int BY2,
         int OX1, int OX2, int OY1, int OY2,
         int AOFF, int BOFF, int OOFF>
__device__ __forceinline__ void step(float* __restrict__ lds, int tid) {
    constexpr int XB = X2 / TX;
    constexpr int TILES = X1 * XB * Y1;
    for (int r = tid; r < TILES; r += NT) {
        const int x1 = r / (XB * Y1);
        const int rm = r - x1 * (XB * Y1);
        const int xb = rm / Y1;
        const int y1 = rm - xb * Y1;
        const float* __restrict__ Ab = lds + AOFF + x1 * AX1 + xb * TX * AX2;
        const float* __restrict__ Bb = lds + BOFF + y1 * BY1;
        float acc[TX][Y2];
#pragma unroll
        for (int i = 0; i < TX; i++)
#pragma unroll
            for (int t2 = 0; t2 < Y2; t2++) acc[i][t2] = 0.f;
#pragma unroll
        for (int u = 0; u < U; u++) {
#pragma unroll
            for (int l = 0; l < L; l++) {
                float a[TX];
#pragma unroll
                for (int i = 0; i < TX; i++) a[i] = Ab[i * AX2 + u * AU + l * AL];
                const float* __restrict__ Bp = Bb + u * BU + l * BLS;
#pragma unroll
                for (int t2 = 0; t2 < Y2; t2++) {
                    const float bv = Bp[t2 * BY2];
#pragma unroll
                    for (int i = 0; i < TX; i++) acc[i][t2] += a[i] * bv;
                }
            }
        }
        float* __restrict__ Ob = lds + OOFF + x1 * OX1 + xb * TX * OX2 + y1 * OY1;
#pragma unroll
        for (int i = 0; i < TX; i++)
#pragma unroll
            for (int t2 = 0; t2 < Y2; t2++) Ob[i * OX2 + t2 * OY2] = acc[i][t2];
    }
}

// ---------------------------------------------------------------------------
// Main: one block = one sample (128 thr). Quadrant contraction; t-staging for
// step k+1 folded into step k's phase; 4 big LDS buffers renamed.
// ---------------------------------------------------------------------------
__global__ __launch_bounds__(NT) void peps_main(const float* __restrict__ x, PW pw,
                                                const float* __restrict__ gram,
                                                float* __restrict__ out) {
    __shared__ float lds[ASZ];
    __shared__ float cfa[16], cfb[16];
    __shared__ float red[2][10];

    const int tid = threadIdx.x;
    const int s = blockIdx.x;

    // per-node normalized coefficients: t_ij = (a*w0 + b*w1)/||.||
    if (tid < 16) {
        const float a = x[s * 32 + tid * 2 + 0];
        const float b = x[s * 32 + tid * 2 + 1];
        const float g0 = gram[tid * 3 + 0], g1 = gram[tid * 3 + 1], g2 = gram[tid * 3 + 2];
        const float inv = 1.f / sqrtf(a * a * g0 + 2.f * a * b * g1 + b * b * g2);
        cfa[tid] = a * inv; cfb[tid] = b * inv;
    }
    __syncthreads();

#define TM(M, DST, WI) tmat<M, DST>(lds, pw.w[WI], cfa[WI], cfb[WI], tid)
#define SYNC __syncthreads()

    // pre: stage t00, t01
    TM(36, SC, 0); TM(216, SA, 1); SYNC;
    // P1: S1 TL1[v00,v01,h01]=sum_{h00} t00*t01 -> PB ; stage t10
    step<1, 6, 6, 6, 6, 1, 1,  0, 6, 1, 0,   36, 0, 6, 1,   0, 36, 6, 1,  SC, SA, PBo>(lds, tid);
    TM(216, SB, 4); SYNC;
    // P2: S2 TL2[v01,h01,v10,h10]=sum_{v00} TL1*t10 -> BA ; stage t11 -> BB
    step<1, 36, 6, 6, 6, 1, 2,  0, 1, 36, 0,  36, 0, 6, 1,   0, 36, 6, 1,  PBo, SB, BA>(lds, tid);
    TM(1296, BB, 5); SYNC;
    // P3: S3 TL[h01,v10,v11,h11]=sum_{v01,h10} TL2*t11 -> BC ; stage t02,t03
    step<6, 6, 6, 6, 6, 6, 2,  36, 6, 216, 1, 216, 36, 6, 1, 216, 36, 6, 1, BA, BB, BC>(lds, tid);
    TM(216, SA, 2); TM(36, SC, 3); SYNC;
    // P4: S4 TR1[h01,v02,v03]=sum_{h02} t02*t03 -> PB ; stage t13
    step<1, 36, 1, 6, 6, 1, 1,  0, 6, 1, 0,   6, 0, 0, 1,    0, 6, 0, 1,   SA, SC, PBo>(lds, tid);
    TM(216, SB, 7); SYNC;
    // P5: S5 TR2[h01,v02,h12,v13]=sum_{v03} TR1*t13 -> BA ; stage t12 -> BB
    step<1, 36, 6, 6, 6, 1, 2,  0, 6, 1, 0,   36, 0, 6, 1,   0, 36, 6, 1,  PBo, SB, BA>(lds, tid);
    TM(1296, BB, 6); SYNC;
    // P6: S6 TR'[h11,v12,h01,v13]=sum_{v02,h12} t12*TR2 -> BD ; stage t30,t20
    step<6, 6, 6, 6, 6, 6, 2,  36, 6, 216, 1, 36, 6, 216, 1, 216, 36, 6, 1, BB, BA, BD>(lds, tid);
    TM(36, SC, 12); TM(216, SA, 8); SYNC;
    // P7: S7 TOP[v10,v11,v12,v13]=sum_{h01,h11} TL*TR' -> BA ;
    //     S8 BL1[h30,v10,h20]=sum_{v20} t30*t20 -> PB ; stage t31
    step<6, 6, 6, 6, 6, 6, 2,  36, 6, 216, 1, 6, 216, 36, 1, 216, 36, 6, 1, BC, BD, BA>(lds, tid);
    step<1, 6, 6, 6, 6, 1, 1,  0, 1, 6, 0,    6, 0, 36, 1,   0, 36, 6, 1,  SC, SA, PBo>(lds, tid);
    TM(216, SB, 13); SYNC;
    // P8: S9 BL2[v10,h20,v21,h31]=sum_{h30} BL1*t31 -> BC ; stage t21 -> BD
    step<1, 36, 6, 6, 6, 1, 2,  0, 1, 36, 0,  6, 0, 36, 1,   0, 36, 6, 1,  PBo, SB, BC>(lds, tid);
    TM(1296, BD, 9); SYNC;
    // P9: S10 BL[v10,h31,v11,h21]=sum_{h20,v21} BL2*t21 -> BB ; stage t23,t33
    step<6, 6, 6, 6, 6, 6, 2,  216, 1, 36, 6, 36, 6, 216, 1, 216, 36, 6, 1, BC, BD, BB>(lds, tid);
    TM(216, SA, 11); TM(36, SC, 15); SYNC;
    // P10: S11 M1[v12,v13,h31,h21]=sum_{v10,v11} TOP*BL -> BC ;
    //      S12 R1[v13,h22,h32]=sum_{v23} t23*t33 -> PB ; stage t32
    step<6, 6, 6, 6, 6, 6, 2,  6, 1, 216, 36, 216, 6, 36, 1, 216, 36, 6, 1, BA, BB, BC>(lds, tid);
    step<6, 6, 1, 6, 6, 1, 1,  36, 6, 1, 0,   6, 0, 0, 1,    36, 6, 0, 1,  SA, SC, PBo>(lds, tid);
    TM(216, SB, 14); SYNC;
    // P11: S13 R'[v13,h31,v22,h22]=sum_{h32} R1*t32 -> BA
    step<6, 6, 6, 6, 6, 1, 2,  36, 6, 1, 0,   1, 0, 36, 6,   216, 1, 6, 36, PBo, SB, BA>(lds, tid);
    SYNC;
    // P12: S14 E[v12,h21,v22,h22]=sum_{v13,h31} M1*R' -> BB
    step<6, 6, 6, 6, 6, 6, 2,  216, 1, 36, 6, 216, 36, 6, 1, 216, 36, 6, 1, BC, BA, BB>(lds, tid);
    SYNC;
#undef TM
#undef SYNC

    // ---- epilogue: out[o] = sum_e E[e]*(a*w22_0[e,o]+b*w22_1[e,o]); normalize ----
    {
        const float al = cfa[10], be = cfb[10];
        const float* __restrict__ w0 = pw.w[10];
        const float* __restrict__ w1 = w0 + 12960;
        float p[10];
#pragma unroll
        for (int o = 0; o < 10; o++) p[o] = 0.f;
        for (int e = tid; e < 1296; e += NT) {
            const float Ev = lds[BB + e];
            const float* __restrict__ q0 = w0 + e * 10;
            const float* __restrict__ q1 = w1 + e * 10;
#pragma unroll
            for (int o = 0; o < 10; o++) p[o] += Ev * (al * q0[o] + be * q1[o]);
        }
#pragma unroll
        for (int o = 0; o < 10; o++)
            for (int off = 32; off > 0; off >>= 1)
                p[o] += __shfl_down(p[o], off, 64);
        const int lane = tid & 63, wv = tid >> 6;
        if (lane == 0) {
#pragma unroll
            for (int o = 0; o < 10; o++) red[wv][o] = p[o];
        }
        __syncthreads();
        if (tid == 0) {
            float r[10];
            float ss = 0.f;
#pragma unroll
            for (int o = 0; o < 10; o++) {
                r[o] = red[0][o] + red[1][o];
                ss += r[o] * r[o];
            }
            const float inv = 1.f / sqrtf(ss);
#pragma unroll
            for (int o = 0; o < 10; o++) out[s * 10 + o] = r[o] * inv;
        }
    }
}

extern "C" void kernel_launch(void* const* d_in, const int* in_sizes, int n_in,
                              void* d_out, int out_size, void* d_ws, size_t ws_size,
                              hipStream_t stream) {
    PW pw;
    for (int k = 0; k < 16; k++) {
        pw.w[k] = (const float*)d_in[1 + k];
        pw.perp[k] = in_sizes[1 + k] / 2;   // elements per physical slice
    }
    float* gram = (float*)d_ws;             // 48 floats
    gram16<<<16, NTG, 0, stream>>>(pw, gram);

    const float* x = (const float*)d_in[0];
    const int B = out_size / 10;            // 2048 samples
    peps_main<<<B, NT, 0, stream>>>(x, pw, gram, (float*)d_out);
}